// Round 1
// 385.908 us; speedup vs baseline: 1.1167x; 1.1167x over previous
//
#include <hip/hip_runtime.h>
#include <hip/hip_bf16.h>

typedef __bf16 bf16;
typedef bf16 bf16x4 __attribute__((ext_vector_type(4)));
typedef bf16 bf16x8 __attribute__((ext_vector_type(8)));
typedef float f32x4 __attribute__((ext_vector_type(4)));

#define GLD_LDS16(gptr, lptr) \
  __builtin_amdgcn_global_load_lds((const __attribute__((address_space(1))) unsigned int*)(gptr), \
                                   (__attribute__((address_space(3))) unsigned int*)(lptr), 16, 0, 0)

// ---------------------------------------------------------------------------
// fp32 -> bf16 elementwise convert (8 elems/thread)
// ---------------------------------------------------------------------------
__global__ __launch_bounds__(256) void f32_to_bf16(const float* __restrict__ in,
                                                   bf16* __restrict__ out) {
  const size_t i = ((size_t)blockIdx.x * 256 + threadIdx.x) * 8;
  float4 a = *(const float4*)(in + i);
  float4 b = *(const float4*)(in + i + 4);
  bf16x8 o;
  o[0] = (bf16)a.x; o[1] = (bf16)a.y; o[2] = (bf16)a.z; o[3] = (bf16)a.w;
  o[4] = (bf16)b.x; o[5] = (bf16)b.y; o[6] = (bf16)b.z; o[7] = (bf16)b.w;
  *(bf16x8*)(out + i) = o;
}

// ---------------------------------------------------------------------------
// Transpose fp32 (R x C) -> bf16 (C x R), 32x32 LDS tiles
// ---------------------------------------------------------------------------
__global__ __launch_bounds__(256) void transpose_f32_bf16(const float* __restrict__ in,
                                                          bf16* __restrict__ out,
                                                          int R, int C) {
  __shared__ float tile[32][33];
  const int bx = blockIdx.x * 32;
  const int by = blockIdx.y * 32;
  const int tx = threadIdx.x & 31;
  const int ty = threadIdx.x >> 5;
#pragma unroll
  for (int i = 0; i < 4; i++) {
    int r = by + ty + i * 8;
    tile[ty + i * 8][tx] = in[(size_t)r * C + bx + tx];
  }
  __syncthreads();
#pragma unroll
  for (int i = 0; i < 4; i++) {
    int r = bx + ty + i * 8;
    out[(size_t)r * R + by + tx] = (bf16)tile[tx][ty + i * 8];
  }
}

// ---------------------------------------------------------------------------
// Rope cos/sin table: ctab[t][f] = {cos(t*invf(f)), sin(t*invf(f))}, t<4096, f<32.
// Math bit-identical to the previous inline epilogue version.
// ---------------------------------------------------------------------------
__global__ __launch_bounds__(256) void rope_tab(float2* __restrict__ ctab) {
  const int idx = blockIdx.x * 256 + threadIdx.x;   // 131072 total
  const int t = idx >> 5, f = idx & 31;
  const float invf = (float)exp(-((double)f / 32.0) * log(500000.0));
  float sn, cs;
  sincosf((float)t * invf, &sn, &cs);
  ctab[idx] = make_float2(cs, sn);
}

// ---------------------------------------------------------------------------
// 256x256 tile GEMM core, BK=64, 8 waves (512 thr), 4-quadrant phase pipeline.
// LDS: As/Bs = [dbuf 2][half 2][128 rows][64 cols] bf16 (2x16KB each operand,
// 128 KiB total). Staging via global_load_lds width=16, linear LDS dest,
// chunk-XOR swizzle (phys 16B-chunk = logical ^ (row&7)) applied on the global
// source so ds_read_b128 fragment loads are bank-conflict-free.
// Per wave: output 128x64 (wm=wave>>2 picks A-half, wn=wave&3 picks B cols).
// Phase p computes one C-quadrant over full K=64 (16 MFMA), with raw s_barrier
// + lgkmcnt(0) + sched_barrier(0) + setprio around the MFMA cluster; next-tile
// staging front-loaded into phases 1-3; single vmcnt(0) at the tile boundary.
// ---------------------------------------------------------------------------
__device__ __forceinline__ void gemm256_core(const bf16* __restrict__ A,
                                             const bf16* __restrict__ BT,
                                             const int K, const int m0, const int n0,
                                             bf16* __restrict__ As, bf16* __restrict__ Bs,
                                             f32x4 acc[8][4]) {
  const int tid = threadIdx.x;
  const int lane = tid & 63;
  const int w = tid >> 6;
  const int wm = w >> 2, wn = w & 3;

#pragma unroll
  for (int i = 0; i < 8; i++)
#pragma unroll
    for (int j = 0; j < 4; j++) acc[i][j] = f32x4{0.f, 0.f, 0.f, 0.f};

  // staging addressing: wave w deposits 1KB/round at half-buffer + w*1024B,
  // lane implicit offset = lane*16B -> row = w*8 + (lane>>3) (+64 round 1),
  // phys chunk = lane&7, logical chunk = phys ^ (row&7).
  const int rA = (w << 3) + (lane >> 3);
  const int colS = (((lane & 7) ^ ((lane >> 3) & 7)) << 3);
  const bf16* Ag = A + (size_t)(m0 + rA) * K + colS;
  const bf16* Bg = BT + (size_t)(n0 + rA) * K + colS;
  bf16* AsW = As + w * 512;
  bf16* BsW = Bs + w * 512;

#define STAGE2(G, L, h, k0)                                                        \
  do {                                                                             \
    GLD_LDS16((G) + (size_t)(h) * 128 * K + (k0), (L) + (h) * 8192);               \
    GLD_LDS16((G) + (size_t)(h) * 128 * K + (size_t)64 * K + (k0),                 \
              (L) + (h) * 8192 + 4096);                                            \
  } while (0)

  // prologue: stage tile 0 into dbuf 0, drain, barrier
  STAGE2(Ag, AsW, 0, 0);
  STAGE2(Ag, AsW, 1, 0);
  STAGE2(Bg, BsW, 0, 0);
  STAGE2(Bg, BsW, 1, 0);
  asm volatile("s_waitcnt vmcnt(0)" ::: "memory");
  __builtin_amdgcn_s_barrier();

  // fragment-read addressing
  const int fr = lane & 15;
  const int kq = lane >> 4;
  const int swz = fr & 7;                 // (row & 7) for all fragment rows
  const int pc0 = ((kq) ^ swz) << 3;      // kk=0 phys chunk byte.. (elem) offset
  const int pc1 = ((4 + kq) ^ swz) << 3;  // kk=1

  bf16x8 af[4][2], bv[4][2];
  const int NT = K >> 6;

  for (int kt = 0; kt < NT; ++kt) {
    const int db = kt & 1;
    const bf16* Ah = As + db * 16384 + wm * 8192;         // this wave's A half
    const bf16* Bh = Bs + db * 16384 + (wn >> 1) * 8192;  // this wave's B half
    const int cb = (wn & 1) * 64;                         // col base within half
    const int nk0 = (kt + 1) << 6;
    const bool stg = (kt + 1 < NT);
    bf16* AsN = AsW + (db ^ 1) * 16384;
    bf16* BsN = BsW + (db ^ 1) * 16384;

    // ---------- phase 1: quadrant (mh=0, nh=0); stage next A0+A1 ----------
#pragma unroll
    for (int mi = 0; mi < 4; mi++) {
      af[mi][0] = *(const bf16x8*)(Ah + (mi * 16 + fr) * 64 + pc0);
      af[mi][1] = *(const bf16x8*)(Ah + (mi * 16 + fr) * 64 + pc1);
    }
#pragma unroll
    for (int ni = 0; ni < 2; ni++) {
      bv[ni][0] = *(const bf16x8*)(Bh + (cb + ni * 16 + fr) * 64 + pc0);
      bv[ni][1] = *(const bf16x8*)(Bh + (cb + ni * 16 + fr) * 64 + pc1);
    }
    if (stg) { STAGE2(Ag, AsN, 0, nk0); STAGE2(Ag, AsN, 1, nk0); }
    __builtin_amdgcn_s_barrier();
    asm volatile("s_waitcnt lgkmcnt(0)" ::: "memory");
    __builtin_amdgcn_sched_barrier(0);
    __builtin_amdgcn_s_setprio(1);
#pragma unroll
    for (int mi = 0; mi < 4; mi++)
#pragma unroll
      for (int ni = 0; ni < 2; ni++) {
        acc[mi][ni] = __builtin_amdgcn_mfma_f32_16x16x32_bf16(af[mi][0], bv[ni][0], acc[mi][ni], 0, 0, 0);
        acc[mi][ni] = __builtin_amdgcn_mfma_f32_16x16x32_bf16(af[mi][1], bv[ni][1], acc[mi][ni], 0, 0, 0);
      }
    __builtin_amdgcn_s_setprio(0);
    __builtin_amdgcn_s_barrier();

    // ---------- phase 2: quadrant (mh=0, nh=1); stage next B0 ----------
#pragma unroll
    for (int ni = 2; ni < 4; ni++) {
      bv[ni][0] = *(const bf16x8*)(Bh + (cb + ni * 16 + fr) * 64 + pc0);
      bv[ni][1] = *(const bf16x8*)(Bh + (cb + ni * 16 + fr) * 64 + pc1);
    }
    if (stg) STAGE2(Bg, BsN, 0, nk0);
    __builtin_amdgcn_s_barrier();
    asm volatile("s_waitcnt lgkmcnt(0)" ::: "memory");
    __builtin_amdgcn_sched_barrier(0);
    __builtin_amdgcn_s_setprio(1);
#pragma unroll
    for (int mi = 0; mi < 4; mi++)
#pragma unroll
      for (int ni = 2; ni < 4; ni++) {
        acc[mi][ni] = __builtin_amdgcn_mfma_f32_16x16x32_bf16(af[mi][0], bv[ni][0], acc[mi][ni], 0, 0, 0);
        acc[mi][ni] = __builtin_amdgcn_mfma_f32_16x16x32_bf16(af[mi][1], bv[ni][1], acc[mi][ni], 0, 0, 0);
      }
    __builtin_amdgcn_s_setprio(0);
    __builtin_amdgcn_s_barrier();

    // ---------- phase 3: quadrant (mh=1, nh=1); stage next B1 ----------
#pragma unroll
    for (int mi = 0; mi < 4; mi++) {
      af[mi][0] = *(const bf16x8*)(Ah + (64 + mi * 16 + fr) * 64 + pc0);
      af[mi][1] = *(const bf16x8*)(Ah + (64 + mi * 16 + fr) * 64 + pc1);
    }
    if (stg) STAGE2(Bg, BsN, 1, nk0);
    __builtin_amdgcn_s_barrier();
    asm volatile("s_waitcnt lgkmcnt(0)" ::: "memory");
    __builtin_amdgcn_sched_barrier(0);
    __builtin_amdgcn_s_setprio(1);
#pragma unroll
    for (int mi = 0; mi < 4; mi++)
#pragma unroll
      for (int ni = 2; ni < 4; ni++) {
        acc[mi + 4][ni] = __builtin_amdgcn_mfma_f32_16x16x32_bf16(af[mi][0], bv[ni][0], acc[mi + 4][ni], 0, 0, 0);
        acc[mi + 4][ni] = __builtin_amdgcn_mfma_f32_16x16x32_bf16(af[mi][1], bv[ni][1], acc[mi + 4][ni], 0, 0, 0);
      }
    __builtin_amdgcn_s_setprio(0);
    __builtin_amdgcn_s_barrier();

    // ---------- phase 4: quadrant (mh=1, nh=0); af from ph3, bv[0..1] from ph1.
    // Tile-boundary drain: vmcnt(0) ensures next tile's LDS deposits landed. ----
    __builtin_amdgcn_s_setprio(1);
#pragma unroll
    for (int mi = 0; mi < 4; mi++)
#pragma unroll
      for (int ni = 0; ni < 2; ni++) {
        acc[mi + 4][ni] = __builtin_amdgcn_mfma_f32_16x16x32_bf16(af[mi][0], bv[ni][0], acc[mi + 4][ni], 0, 0, 0);
        acc[mi + 4][ni] = __builtin_amdgcn_mfma_f32_16x16x32_bf16(af[mi][1], bv[ni][1], acc[mi + 4][ni], 0, 0, 0);
      }
    __builtin_amdgcn_s_setprio(0);
    asm volatile("s_waitcnt vmcnt(0)" ::: "memory");
    __builtin_amdgcn_s_barrier();
  }
#undef STAGE2
}

// bijective XCD swizzle (nwg % 8 == 0 for all our grids)
__device__ __forceinline__ void xcd_tile(int& m0, int& n0) {
  const int gx = gridDim.x;
  const int nwg = gx * gridDim.y;
  const int orig = blockIdx.y * gx + blockIdx.x;
  const int cpx = nwg >> 3;
  const int swb = (orig & 7) * cpx + (orig >> 3);
  m0 = (swb / gx) * 256;
  n0 = (swb % gx) * 256;
}

// ---------------------------------------------------------------------------
// QKV GEMM with fused rope(table)+scale+elu+1 epilogue.
// x[16384,1024] bf16 @ WqkvT[3072,1024] bf16 -> head-major qf/kf/vf
// [bh=64][t=4096][d=64]. A wave's 64-col span == one head.
// ---------------------------------------------------------------------------
__global__ __launch_bounds__(512, 2) void gemm_qkv_fused(const bf16* __restrict__ A,
                                                         const bf16* __restrict__ BT,
                                                         const float2* __restrict__ ctab,
                                                         bf16* __restrict__ qfB,
                                                         bf16* __restrict__ kfB,
                                                         bf16* __restrict__ vfB) {
  __shared__ __attribute__((aligned(16))) bf16 As[32768];
  __shared__ __attribute__((aligned(16))) bf16 Bs[32768];
  const int K = 1024;
  int m0, n0;
  xcd_tile(m0, n0);

  f32x4 acc[8][4];
  gemm256_core(A, BT, K, m0, n0, As, Bs, acc);

  const int lane = threadIdx.x & 63;
  const int w = threadIdx.x >> 6;
  const int wm = w >> 2, wn = w & 3;
  const int fr15 = lane & 15;
  const int cb = n0 + wn * 64;            // wave-uniform column block (one head)
  const int p = cb >> 10;                 // 0=q, 1=k, 2=v
  const int hh = (cb & 1023) >> 6;
  const int row00 = m0 + wm * 128 + ((lane >> 4) << 2);
  const int b = row00 >> 12;              // wave-uniform (256-row blocks never straddle batch)
  const size_t base0 = ((size_t)(b * 16 + hh)) * 4096 * 64;

  if (p == 2) {
#pragma unroll
    for (int mi = 0; mi < 8; mi++)
#pragma unroll
      for (int r = 0; r < 4; r++) {
        const int tloc = (row00 + mi * 16 + r) & 4095;
        bf16* dst = vfB + base0 + (size_t)tloc * 64;
#pragma unroll
        for (int ni = 0; ni < 4; ni++) dst[fr15 + ni * 16] = (bf16)acc[mi][ni][r];
      }
  } else {
    bf16* outp = (p == 0) ? qfB : kfB;
    const float scl = (p == 0) ? 0.125f : 1.0f;
#pragma unroll
    for (int mi = 0; mi < 8; mi++)
#pragma unroll
      for (int r = 0; r < 4; r++) {
        const int tloc = (row00 + mi * 16 + r) & 4095;
        const float2* ct = ctab + tloc * 32;
        bf16* dst = outp + base0 + (size_t)tloc * 64;
#pragma unroll
        for (int ni = 0; ni < 2; ni++) {
          const float2 cs2 = ct[fr15 + ni * 16];
          const float x1 = acc[mi][ni][r], x2 = acc[mi][ni + 2][r];
          const float r1 = (x1 * cs2.x - x2 * cs2.y) * scl;
          const float r2 = (x2 * cs2.x + x1 * cs2.y) * scl;
          dst[fr15 + ni * 16] = (bf16)(r1 > 0.f ? r1 + 1.f : __expf(r1));
          dst[fr15 + ni * 16 + 32] = (bf16)(r2 > 0.f ? r2 + 1.f : __expf(r2));
        }
      }
  }
}

// ---------------------------------------------------------------------------
// Plain GEMM (final projection): C fp32 = A bf16 @ BT^T bf16.
// ---------------------------------------------------------------------------
__global__ __launch_bounds__(512, 2) void gemm_bt_f32(const bf16* __restrict__ A,
                                                      const bf16* __restrict__ BT,
                                                      float* __restrict__ C,
                                                      int N, int K) {
  __shared__ __attribute__((aligned(16))) bf16 As[32768];
  __shared__ __attribute__((aligned(16))) bf16 Bs[32768];
  int m0, n0;
  xcd_tile(m0, n0);

  f32x4 acc[8][4];
  gemm256_core(A, BT, K, m0, n0, As, Bs, acc);

  const int lane = threadIdx.x & 63;
  const int w = threadIdx.x >> 6;
  const int wm = w >> 2, wn = w & 3;
  const int col0 = n0 + wn * 64 + (lane & 15);
  const int row00 = m0 + wm * 128 + ((lane >> 4) << 2);
#pragma unroll
  for (int mi = 0; mi < 8; mi++)
#pragma unroll
    for (int ni = 0; ni < 4; ni++)
#pragma unroll
      for (int r = 0; r < 4; r++)
        C[(size_t)(row00 + mi * 16 + r) * N + col0 + ni * 16] = acc[mi][ni][r];
}

// ---------------------------------------------------------------------------
// attn_kv: per (b,h) kv[64][64] = sum_t kf[t] (x) v[t], ksum[64] = sum_t kf[t].
// ---------------------------------------------------------------------------
__global__ __launch_bounds__(256) void attn_kv(const bf16* __restrict__ kfB,
                                               const bf16* __restrict__ vfB,
                                               float* __restrict__ kvg,
                                               float* __restrict__ ksumg) {
  const int bh = blockIdx.x;
  const int t0 = blockIdx.y * 256;
  __shared__ __attribute__((aligned(16))) float kfs[32][68];
  __shared__ __attribute__((aligned(16))) float vfs[32][68];
  const int tid = threadIdx.x;
  const int dq = tid & 15, g = tid >> 4;
  const int tl = tid >> 3, ch = (tid & 7) * 8;

  f32x4 acc[4];
#pragma unroll
  for (int r = 0; r < 4; r++) acc[r] = f32x4{0.f, 0.f, 0.f, 0.f};
  float ksa[4] = {0.f, 0.f, 0.f, 0.f};

  for (int sc = 0; sc < 8; sc++) {
    const size_t rowb = ((size_t)bh * 4096 + t0 + sc * 32 + tl) * 64 + ch;
    bf16x8 k8 = *(const bf16x8*)(kfB + rowb);
    bf16x8 v8 = *(const bf16x8*)(vfB + rowb);
    f32x4 ka, kb, va, vb;
#pragma unroll
    for (int j = 0; j < 4; j++) {
      ka[j] = (float)k8[j]; kb[j] = (float)k8[j + 4];
      va[j] = (float)v8[j]; vb[j] = (float)v8[j + 4];
    }
    *(f32x4*)&kfs[tl][ch] = ka;
    *(f32x4*)&kfs[tl][ch + 4] = kb;
    *(f32x4*)&vfs[tl][ch] = va;
    *(f32x4*)&vfs[tl][ch + 4] = vb;
    __syncthreads();

#pragma unroll 8
    for (int t = 0; t < 32; t++) {
      f32x4 kq = *(const f32x4*)&kfs[t][dq * 4];
      f32x4 vq = *(const f32x4*)&vfs[t][g * 4];
#pragma unroll
      for (int r = 0; r < 4; r++) {
#pragma unroll
        for (int c = 0; c < 4; c++) acc[r][c] += kq[r] * vq[c];
      }
      if (g == 0) {
#pragma unroll
        for (int r = 0; r < 4; r++) ksa[r] += kq[r];
      }
    }
    __syncthreads();
  }

#pragma unroll
  for (int r = 0; r < 4; r++)
#pragma unroll
    for (int c = 0; c < 4; c++)
      atomicAdd(&kvg[(size_t)bh * 4096 + (dq * 4 + r) * 64 + g * 4 + c], acc[r][c]);
  if (g == 0) {
#pragma unroll
    for (int r = 0; r < 4; r++) atomicAdd(&ksumg[bh * 64 + dq * 4 + r], ksa[r]);
  }
}

// ---------------------------------------------------------------------------
// attn_out: out[t] = (qf[t] @ kv) / max(qf[t]·ksum, 1e-6).
// ---------------------------------------------------------------------------
__global__ __launch_bounds__(256) void attn_out(const bf16* __restrict__ qfB,
                                                const float* __restrict__ kvg,
                                                const float* __restrict__ ksumg,
                                                bf16* __restrict__ attn) {
  const int bh = blockIdx.y;
  const int b = bh >> 4, h = bh & 15;
  const int t0 = blockIdx.x * 64;
  __shared__ __attribute__((aligned(16))) float qf[64][68];
  __shared__ __attribute__((aligned(16))) float kvs[64][64];
  __shared__ __attribute__((aligned(16))) float ksums[64];
  const int tid = threadIdx.x;

#pragma unroll
  for (int j = 0; j < 2; j++) {
    int chunk = tid + 256 * j;
    int tl = chunk >> 3, col = (chunk & 7) * 8;
    bf16x8 r = *(const bf16x8*)(qfB + ((size_t)bh * 4096 + t0 + tl) * 64 + col);
    f32x4 a, bb;
#pragma unroll
    for (int q = 0; q < 4; q++) { a[q] = (float)r[q]; bb[q] = (float)r[q + 4]; }
    *(f32x4*)&qf[tl][col] = a;
    *(f32x4*)&qf[tl][col + 4] = bb;
  }
#pragma unroll
  for (int j = 0; j < 4; j++) {
    int idx = tid + 256 * j;
    *(float4*)&kvs[idx >> 4][(idx & 15) * 4] = *(const float4*)&kvg[(size_t)bh * 4096 + idx * 4];
  }
  if (tid < 64) ksums[tid] = ksumg[bh * 64 + tid];
  __syncthreads();

  const int tr = tid >> 4, cc = tid & 15;
  f32x4 acc[4];
#pragma unroll
  for (int r = 0; r < 4; r++) acc[r] = f32x4{0.f, 0.f, 0.f, 0.f};
  f32x4 dn = f32x4{0.f, 0.f, 0.f, 0.f};

  for (int d2 = 0; d2 < 64; d2++) {
    f32x4 kv4 = *(const f32x4*)&kvs[d2][cc * 4];
    float ks = ksums[d2];
#pragma unroll
    for (int r = 0; r < 4; r++) {
      float qv = qf[tr * 4 + r][d2];
      acc[r] += qv * kv4;
      dn[r] += qv * ks;
    }
  }

#pragma unroll
  for (int r = 0; r < 4; r++) {
    const float rdn = 1.f / fmaxf(dn[r], 1e-6f);
    bf16x4 o;
#pragma unroll
    for (int c = 0; c < 4; c++) o[c] = (bf16)(acc[r][c] * rdn);
    *(bf16x4*)(attn + ((size_t)(b * 4096) + t0 + tr * 4 + r) * 1024 + h * 64 + cc * 4) = o;
  }
}

// ---------------------------------------------------------------------------
// Workspace layout (bytes):
//   kvg   f32  [64*64*64]     @ 0          size   1048576
//   ksumg f32  [64*64]        @ 1048576    size     16384
//   WqkvT bf16 [3072,1024]    @ 1064960    size   6291456
//   WoutT bf16 [1024,1024]    @ 7356416    size   2097152
//   attn  bf16 [16384,1024]   @ 9453568    size  33554432
//     (first 1 MiB doubles as ctab float2[4096][32] — consumed by gemm_qkv,
//      overwritten later by attn_out before gemm_bt reads it)
//   qfB   bf16 [64,4096,64]   @ 43008000   size  33554432
//   kfB   bf16 [64,4096,64]   @ 76562432   size  33554432
//   vfB   bf16 [64,4096,64]   @ 110116864  size  33554432
//   xB    bf16 [16384,1024]   @ 143671296  size  33554432
//   total 177225728 (~169 MiB)
// ---------------------------------------------------------------------------
extern "C" void kernel_launch(void* const* d_in, const int* in_sizes, int n_in,
                              void* d_out, int out_size, void* d_ws, size_t ws_size,
                              hipStream_t stream) {
  if (ws_size < 177225728ULL) return;

  const float* x = (const float*)d_in[0];
  const float* Wqkv = (const float*)d_in[1];
  const float* Wout = (const float*)d_in[2];
  float* out = (float*)d_out;
  char* ws = (char*)d_ws;

  float* kvg = (float*)(ws);
  float* ksumg = (float*)(ws + 1048576);
  bf16* WqkvT = (bf16*)(ws + 1064960);
  bf16* WoutT = (bf16*)(ws + 7356416);
  bf16* attn = (bf16*)(ws + 9453568);
  float2* ctab = (float2*)(ws + 9453568);   // aliases attn head; see layout note
  bf16* qfB = (bf16*)(ws + 43008000);
  bf16* kfB = (bf16*)(ws + 76562432);
  bf16* vfB = (bf16*)(ws + 110116864);
  bf16* xB = (bf16*)(ws + 143671296);

  hipMemsetAsync(ws, 0, 1048576 + 16384, stream);

  rope_tab<<<512, 256, 0, stream>>>(ctab);
  f32_to_bf16<<<16777216 / (256 * 8), 256, 0, stream>>>(x, xB);
  transpose_f32_bf16<<<dim3(3072 / 32, 1024 / 32), 256, 0, stream>>>(Wqkv, WqkvT, 1024, 3072);
  transpose_f32_bf16<<<dim3(1024 / 32, 1024 / 32), 256, 0, stream>>>(Wout, WoutT, 1024, 1024);

  // qkv = x @ W_qkv with fused rope/scale/elu+1 -> head-major qf/kf/vf
  gemm_qkv_fused<<<dim3(3072 / 256, 16384 / 256), 512, 0, stream>>>(xB, WqkvT, ctab, qfB, kfB, vfB);

  // linear attention core
  attn_kv<<<dim3(64, 16), 256, 0, stream>>>(kfB, vfB, kvg, ksumg);
  attn_out<<<dim3(64, 64), 256, 0, stream>>>(qfB, kvg, ksumg, attn);

  // y = attn @ W_out -> fp32 d_out
  gemm_bt_f32<<<dim3(1024 / 256, 16384 / 256), 512, 0, stream>>>(attn, WoutT, out, 1024, 1024);
}

// Round 2
// 385.311 us; speedup vs baseline: 1.1184x; 1.0015x over previous
//
#include <hip/hip_runtime.h>
#include <hip/hip_bf16.h>

typedef __bf16 bf16;
typedef bf16 bf16x4 __attribute__((ext_vector_type(4)));
typedef bf16 bf16x8 __attribute__((ext_vector_type(8)));
typedef float f32x4 __attribute__((ext_vector_type(4)));

#define GLD_LDS16(gptr, lptr) \
  __builtin_amdgcn_global_load_lds((const __attribute__((address_space(1))) unsigned int*)(gptr), \
                                   (__attribute__((address_space(3))) unsigned int*)(lptr), 16, 0, 0)

// ---------------------------------------------------------------------------
// fp32 -> bf16 elementwise convert (8 elems/thread)
// ---------------------------------------------------------------------------
__global__ __launch_bounds__(256) void f32_to_bf16(const float* __restrict__ in,
                                                   bf16* __restrict__ out) {
  const size_t i = ((size_t)blockIdx.x * 256 + threadIdx.x) * 8;
  float4 a = *(const float4*)(in + i);
  float4 b = *(const float4*)(in + i + 4);
  bf16x8 o;
  o[0] = (bf16)a.x; o[1] = (bf16)a.y; o[2] = (bf16)a.z; o[3] = (bf16)a.w;
  o[4] = (bf16)b.x; o[5] = (bf16)b.y; o[6] = (bf16)b.z; o[7] = (bf16)b.w;
  *(bf16x8*)(out + i) = o;
}

// ---------------------------------------------------------------------------
// Transpose fp32 (R x C) -> bf16 (C x R), 32x32 LDS tiles
// ---------------------------------------------------------------------------
__global__ __launch_bounds__(256) void transpose_f32_bf16(const float* __restrict__ in,
                                                          bf16* __restrict__ out,
                                                          int R, int C) {
  __shared__ float tile[32][33];
  const int bx = blockIdx.x * 32;
  const int by = blockIdx.y * 32;
  const int tx = threadIdx.x & 31;
  const int ty = threadIdx.x >> 5;
#pragma unroll
  for (int i = 0; i < 4; i++) {
    int r = by + ty + i * 8;
    tile[ty + i * 8][tx] = in[(size_t)r * C + bx + tx];
  }
  __syncthreads();
#pragma unroll
  for (int i = 0; i < 4; i++) {
    int r = bx + ty + i * 8;
    out[(size_t)r * R + by + tx] = (bf16)tile[tx][ty + i * 8];
  }
}

// ---------------------------------------------------------------------------
// Rope cos/sin table: ctab[t][f] = {cos(t*invf(f)), sin(t*invf(f))}, t<4096, f<32.
// ---------------------------------------------------------------------------
__global__ __launch_bounds__(256) void rope_tab(float2* __restrict__ ctab) {
  const int idx = blockIdx.x * 256 + threadIdx.x;   // 131072 total
  const int t = idx >> 5, f = idx & 31;
  const float invf = (float)exp(-((double)f / 32.0) * log(500000.0));
  float sn, cs;
  sincosf((float)t * invf, &sn, &cs);
  ctab[idx] = make_float2(cs, sn);
}

// ---------------------------------------------------------------------------
// 256x256 tile GEMM core, BK=64, 8 waves (512 thr).
// K-HALF phasing with counted vmcnt (T3+T4): each phase computes ALL acc for a
// 32-wide k-slice (32 MFMA), staging is by k-half (4 GLD_LDS16 per half:
// A rows 0-127, A rows 128-255, B likewise). The half needed by the next phase
// was staged 2 phases earlier, so every inter-phase wait is vmcnt(8) (keeps the
// 8 newest loads in flight); drain-to-0 happens only in the final K-tile.
//
// LDS: As/Bs = [db 2][khalf 2][row 256][col 32] bf16 (16KB per region, 64KB per
// operand, 128 KiB total). GLD dest is linear (uniform base + lane*16B);
// bank-conflict-free ds_read_b128 via chunk-XOR swizzle: phys 16B-chunk =
// logical ^ ((row>>1)&3), applied on the global source (both-sides rule #21).
//
// In-flight-write vs read disjointness (steady state, computing tile kt from
// buf[db]): outstanding GLDs target {khi(kt+1)->buf[db^1].khi, klo(kt+2)->
// buf[db].klo after phase B issue} while reads touch buf[db].{klo|khi} of tile
// kt -- klo(kt) reads end (barrier) before klo(kt+2) is issued; khi region of
// buf[db^1] was last read in tile kt-1 (barrier-separated). All verified per
// phase; vmcnt counts: see comments at each wait.
// ---------------------------------------------------------------------------
__device__ __forceinline__ void gemm256_core(const bf16* __restrict__ A,
                                             const bf16* __restrict__ BT,
                                             const int K, const int m0, const int n0,
                                             bf16* __restrict__ As, bf16* __restrict__ Bs,
                                             f32x4 acc[8][4]) {
  const int tid = threadIdx.x;
  const int lane = tid & 63;
  const int w = tid >> 6;
  const int wm = w >> 2, wn = w & 3;

#pragma unroll
  for (int i = 0; i < 8; i++)
#pragma unroll
    for (int j = 0; j < 4; j++) acc[i][j] = f32x4{0.f, 0.f, 0.f, 0.f};

  // staging: thread covers (row = tid>>2 [+128 for round 1], 16B chunk = tid&3);
  // logical chunk = phys ^ ((row>>1)&3) = (tid&3) ^ ((tid>>3)&3).
  const int lch = (tid & 3) ^ ((tid >> 3) & 3);
  const bf16* Ag = A + (size_t)(m0 + (tid >> 2)) * K + lch * 8;
  const bf16* Bg = BT + (size_t)(n0 + (tid >> 2)) * K + lch * 8;
  const int wb = w * 512;  // wave-uniform LDS base within a region (elems)

#define STG(kh, db, k0)                                                   \
  do {                                                                    \
    bf16* aD = As + ((db) * 2 + (kh)) * 8192 + wb;                        \
    bf16* bD = Bs + ((db) * 2 + (kh)) * 8192 + wb;                        \
    const size_t go = (size_t)(k0) + (kh) * 32;                           \
    GLD_LDS16(Ag + go, aD);                                               \
    GLD_LDS16(Ag + (size_t)128 * K + go, aD + 4096);                      \
    GLD_LDS16(Bg + go, bD);                                               \
    GLD_LDS16(Bg + (size_t)128 * K + go, bD + 4096);                      \
  } while (0)

  // fragment-read addressing: row = {wm*128|wn*64} + i*16 + fr, chunk kq=lane>>4,
  // phys chunk = kq ^ ((fr>>1)&3) (row>>1 & 3 == fr>>1 & 3 since bases = 0 mod 8).
  const int fr = lane & 15;
  const int kq = lane >> 4;
  const int frow = fr * 32 + ((kq ^ ((fr >> 1) & 3)) << 3);
  const int aro = wm * 4096;
  const int bro = wn * 2048;

#define LOADFRAGS(kh, db)                                                 \
  const bf16* Ap = As + ((db) * 2 + (kh)) * 8192 + aro + frow;            \
  const bf16* Bp = Bs + ((db) * 2 + (kh)) * 8192 + bro + frow;            \
  bf16x8 af[8], bv[4];                                                    \
  _Pragma("unroll") for (int mi = 0; mi < 8; mi++)                        \
      af[mi] = *(const bf16x8*)(Ap + mi * 512);                           \
  _Pragma("unroll") for (int ni = 0; ni < 4; ni++)                        \
      bv[ni] = *(const bf16x8*)(Bp + ni * 512);

#define MFMA32                                                            \
  __builtin_amdgcn_s_setprio(1);                                          \
  _Pragma("unroll") for (int mi = 0; mi < 8; mi++)                        \
  _Pragma("unroll") for (int ni = 0; ni < 4; ni++)                        \
      acc[mi][ni] = __builtin_amdgcn_mfma_f32_16x16x32_bf16(              \
          af[mi], bv[ni], acc[mi][ni], 0, 0, 0);                          \
  __builtin_amdgcn_s_setprio(0);

  // prologue: klo(0), khi(0), klo(1) staged; wait oldest 4 (= klo(0)) landed.
  STG(0, 0, 0);
  STG(1, 0, 0);
  if (K > 64) {
    STG(0, 1, 64);
    asm volatile("s_waitcnt vmcnt(8)" ::: "memory");
  } else {
    asm volatile("s_waitcnt vmcnt(4)" ::: "memory");
  }
  __builtin_amdgcn_s_barrier();

  const int NT = K >> 6;
  for (int kt = 0; kt < NT; ++kt) {
    const int db = kt & 1;
    // ---------------- phase A: k-slice [kt*64, kt*64+32) ----------------
    {
      LOADFRAGS(0, db);
      if (kt + 1 < NT) STG(1, db ^ 1, (kt + 1) * 64);  // khi(kt+1)
      __builtin_amdgcn_s_barrier();
      asm volatile("s_waitcnt lgkmcnt(0)" ::: "memory");
      __builtin_amdgcn_sched_barrier(0);
      MFMA32;
      // need khi(kt) landed; newer in flight: klo(kt+1)[4] + khi(kt+1)[4]
      if (kt + 1 < NT) asm volatile("s_waitcnt vmcnt(8)" ::: "memory");
      else             asm volatile("s_waitcnt vmcnt(0)" ::: "memory");
      __builtin_amdgcn_s_barrier();
    }
    // ---------------- phase B: k-slice [kt*64+32, kt*64+64) ----------------
    {
      LOADFRAGS(1, db);
      if (kt + 2 < NT) STG(0, db, (kt + 2) * 64);      // klo(kt+2)
      __builtin_amdgcn_s_barrier();
      asm volatile("s_waitcnt lgkmcnt(0)" ::: "memory");
      __builtin_amdgcn_sched_barrier(0);
      MFMA32;
      // need klo(kt+1) landed; newer: khi(kt+1)[4] + klo(kt+2)[4]
      if (kt + 2 < NT)      asm volatile("s_waitcnt vmcnt(8)" ::: "memory");
      else if (kt + 1 < NT) asm volatile("s_waitcnt vmcnt(4)" ::: "memory");
      __builtin_amdgcn_s_barrier();
    }
  }
#undef STG
#undef LOADFRAGS
#undef MFMA32
}

// bijective XCD swizzle (nwg % 8 == 0 for all our grids)
__device__ __forceinline__ void xcd_tile(int& m0, int& n0) {
  const int gx = gridDim.x;
  const int nwg = gx * gridDim.y;
  const int orig = blockIdx.y * gx + blockIdx.x;
  const int cpx = nwg >> 3;
  const int swb = (orig & 7) * cpx + (orig >> 3);
  m0 = (swb / gx) * 256;
  n0 = (swb % gx) * 256;
}

// ---------------------------------------------------------------------------
// QKV GEMM with fused rope(table)+scale+elu+1 epilogue.
// x[16384,1024] bf16 @ WqkvT[3072,1024] bf16 -> head-major qf/kf/vf
// [bh=64][t=4096][d=64]. A wave's 64-col span == one head.
// ---------------------------------------------------------------------------
__global__ __launch_bounds__(512, 2) void gemm_qkv_fused(const bf16* __restrict__ A,
                                                         const bf16* __restrict__ BT,
                                                         const float2* __restrict__ ctab,
                                                         bf16* __restrict__ qfB,
                                                         bf16* __restrict__ kfB,
                                                         bf16* __restrict__ vfB) {
  __shared__ __attribute__((aligned(16))) bf16 As[32768];
  __shared__ __attribute__((aligned(16))) bf16 Bs[32768];
  const int K = 1024;
  int m0, n0;
  xcd_tile(m0, n0);

  f32x4 acc[8][4];
  gemm256_core(A, BT, K, m0, n0, As, Bs, acc);

  const int lane = threadIdx.x & 63;
  const int w = threadIdx.x >> 6;
  const int wm = w >> 2, wn = w & 3;
  const int fr15 = lane & 15;
  const int cb = n0 + wn * 64;            // wave-uniform column block (one head)
  const int p = cb >> 10;                 // 0=q, 1=k, 2=v
  const int hh = (cb & 1023) >> 6;
  const int row00 = m0 + wm * 128 + ((lane >> 4) << 2);
  const int b = row00 >> 12;              // wave-uniform (256-row blocks never straddle batch)
  const size_t base0 = ((size_t)(b * 16 + hh)) * 4096 * 64;

  if (p == 2) {
#pragma unroll
    for (int mi = 0; mi < 8; mi++)
#pragma unroll
      for (int r = 0; r < 4; r++) {
        const int tloc = (row00 + mi * 16 + r) & 4095;
        bf16* dst = vfB + base0 + (size_t)tloc * 64;
#pragma unroll
        for (int ni = 0; ni < 4; ni++) dst[fr15 + ni * 16] = (bf16)acc[mi][ni][r];
      }
  } else {
    bf16* outp = (p == 0) ? qfB : kfB;
    const float scl = (p == 0) ? 0.125f : 1.0f;
#pragma unroll
    for (int mi = 0; mi < 8; mi++)
#pragma unroll
      for (int r = 0; r < 4; r++) {
        const int tloc = (row00 + mi * 16 + r) & 4095;
        const float2* ct = ctab + tloc * 32;
        bf16* dst = outp + base0 + (size_t)tloc * 64;
#pragma unroll
        for (int ni = 0; ni < 2; ni++) {
          const float2 cs2 = ct[fr15 + ni * 16];
          const float x1 = acc[mi][ni][r], x2 = acc[mi][ni + 2][r];
          const float r1 = (x1 * cs2.x - x2 * cs2.y) * scl;
          const float r2 = (x2 * cs2.x + x1 * cs2.y) * scl;
          dst[fr15 + ni * 16] = (bf16)(r1 > 0.f ? r1 + 1.f : __expf(r1));
          dst[fr15 + ni * 16 + 32] = (bf16)(r2 > 0.f ? r2 + 1.f : __expf(r2));
        }
      }
  }
}

// ---------------------------------------------------------------------------
// Plain GEMM (final projection): C fp32 = A bf16 @ BT^T bf16.
// ---------------------------------------------------------------------------
__global__ __launch_bounds__(512, 2) void gemm_bt_f32(const bf16* __restrict__ A,
                                                      const bf16* __restrict__ BT,
                                                      float* __restrict__ C,
                                                      int N, int K) {
  __shared__ __attribute__((aligned(16))) bf16 As[32768];
  __shared__ __attribute__((aligned(16))) bf16 Bs[32768];
  int m0, n0;
  xcd_tile(m0, n0);

  f32x4 acc[8][4];
  gemm256_core(A, BT, K, m0, n0, As, Bs, acc);

  const int lane = threadIdx.x & 63;
  const int w = threadIdx.x >> 6;
  const int wm = w >> 2, wn = w & 3;
  const int col0 = n0 + wn * 64 + (lane & 15);
  const int row00 = m0 + wm * 128 + ((lane >> 4) << 2);
#pragma unroll
  for (int mi = 0; mi < 8; mi++)
#pragma unroll
    for (int ni = 0; ni < 4; ni++)
#pragma unroll
      for (int r = 0; r < 4; r++)
        C[(size_t)(row00 + mi * 16 + r) * N + col0 + ni * 16] = acc[mi][ni][r];
}

// ---------------------------------------------------------------------------
// attn_kv: per (b,h) kv[64][64] = sum_t kf[t] (x) v[t], ksum[64] = sum_t kf[t].
// ---------------------------------------------------------------------------
__global__ __launch_bounds__(256) void attn_kv(const bf16* __restrict__ kfB,
                                               const bf16* __restrict__ vfB,
                                               float* __restrict__ kvg,
                                               float* __restrict__ ksumg) {
  const int bh = blockIdx.x;
  const int t0 = blockIdx.y * 256;
  __shared__ __attribute__((aligned(16))) float kfs[32][68];
  __shared__ __attribute__((aligned(16))) float vfs[32][68];
  const int tid = threadIdx.x;
  const int dq = tid & 15, g = tid >> 4;
  const int tl = tid >> 3, ch = (tid & 7) * 8;

  f32x4 acc[4];
#pragma unroll
  for (int r = 0; r < 4; r++) acc[r] = f32x4{0.f, 0.f, 0.f, 0.f};
  float ksa[4] = {0.f, 0.f, 0.f, 0.f};

  for (int sc = 0; sc < 8; sc++) {
    const size_t rowb = ((size_t)bh * 4096 + t0 + sc * 32 + tl) * 64 + ch;
    bf16x8 k8 = *(const bf16x8*)(kfB + rowb);
    bf16x8 v8 = *(const bf16x8*)(vfB + rowb);
    f32x4 ka, kb, va, vb;
#pragma unroll
    for (int j = 0; j < 4; j++) {
      ka[j] = (float)k8[j]; kb[j] = (float)k8[j + 4];
      va[j] = (float)v8[j]; vb[j] = (float)v8[j + 4];
    }
    *(f32x4*)&kfs[tl][ch] = ka;
    *(f32x4*)&kfs[tl][ch + 4] = kb;
    *(f32x4*)&vfs[tl][ch] = va;
    *(f32x4*)&vfs[tl][ch + 4] = vb;
    __syncthreads();

#pragma unroll 8
    for (int t = 0; t < 32; t++) {
      f32x4 kq = *(const f32x4*)&kfs[t][dq * 4];
      f32x4 vq = *(const f32x4*)&vfs[t][g * 4];
#pragma unroll
      for (int r = 0; r < 4; r++) {
#pragma unroll
        for (int c = 0; c < 4; c++) acc[r][c] += kq[r] * vq[c];
      }
      if (g == 0) {
#pragma unroll
        for (int r = 0; r < 4; r++) ksa[r] += kq[r];
      }
    }
    __syncthreads();
  }

#pragma unroll
  for (int r = 0; r < 4; r++)
#pragma unroll
    for (int c = 0; c < 4; c++)
      atomicAdd(&kvg[(size_t)bh * 4096 + (dq * 4 + r) * 64 + g * 4 + c], acc[r][c]);
  if (g == 0) {
#pragma unroll
    for (int r = 0; r < 4; r++) atomicAdd(&ksumg[bh * 64 + dq * 4 + r], ksa[r]);
  }
}

// ---------------------------------------------------------------------------
// attn_out: out[t] = (qf[t] @ kv) / max(qf[t]·ksum, 1e-6).
// ---------------------------------------------------------------------------
__global__ __launch_bounds__(256) void attn_out(const bf16* __restrict__ qfB,
                                                const float* __restrict__ kvg,
                                                const float* __restrict__ ksumg,
                                                bf16* __restrict__ attn) {
  const int bh = blockIdx.y;
  const int b = bh >> 4, h = bh & 15;
  const int t0 = blockIdx.x * 64;
  __shared__ __attribute__((aligned(16))) float qf[64][68];
  __shared__ __attribute__((aligned(16))) float kvs[64][64];
  __shared__ __attribute__((aligned(16))) float ksums[64];
  const int tid = threadIdx.x;

#pragma unroll
  for (int j = 0; j < 2; j++) {
    int chunk = tid + 256 * j;
    int tl = chunk >> 3, col = (chunk & 7) * 8;
    bf16x8 r = *(const bf16x8*)(qfB + ((size_t)bh * 4096 + t0 + tl) * 64 + col);
    f32x4 a, bb;
#pragma unroll
    for (int q = 0; q < 4; q++) { a[q] = (float)r[q]; bb[q] = (float)r[q + 4]; }
    *(f32x4*)&qf[tl][col] = a;
    *(f32x4*)&qf[tl][col + 4] = bb;
  }
#pragma unroll
  for (int j = 0; j < 4; j++) {
    int idx = tid + 256 * j;
    *(float4*)&kvs[idx >> 4][(idx & 15) * 4] = *(const float4*)&kvg[(size_t)bh * 4096 + idx * 4];
  }
  if (tid < 64) ksums[tid] = ksumg[bh * 64 + tid];
  __syncthreads();

  const int tr = tid >> 4, cc = tid & 15;
  f32x4 acc[4];
#pragma unroll
  for (int r = 0; r < 4; r++) acc[r] = f32x4{0.f, 0.f, 0.f, 0.f};
  f32x4 dn = f32x4{0.f, 0.f, 0.f, 0.f};

  for (int d2 = 0; d2 < 64; d2++) {
    f32x4 kv4 = *(const f32x4*)&kvs[d2][cc * 4];
    float ks = ksums[d2];
#pragma unroll
    for (int r = 0; r < 4; r++) {
      float qv = qf[tr * 4 + r][d2];
      acc[r] += qv * kv4;
      dn[r] += qv * ks;
    }
  }

#pragma unroll
  for (int r = 0; r < 4; r++) {
    const float rdn = 1.f / fmaxf(dn[r], 1e-6f);
    bf16x4 o;
#pragma unroll
    for (int c = 0; c < 4; c++) o[c] = (bf16)(acc[r][c] * rdn);
    *(bf16x4*)(attn + ((size_t)(b * 4096) + t0 + tr * 4 + r) * 1024 + h * 64 + cc * 4) = o;
  }
}

// ---------------------------------------------------------------------------
// Workspace layout (bytes):
//   kvg   f32  [64*64*64]     @ 0          size   1048576
//   ksumg f32  [64*64]        @ 1048576    size     16384
//   WqkvT bf16 [3072,1024]    @ 1064960    size   6291456
//   WoutT bf16 [1024,1024]    @ 7356416    size   2097152
//   attn  bf16 [16384,1024]   @ 9453568    size  33554432
//     (first 1 MiB doubles as ctab float2[4096][32] — consumed by gemm_qkv,
//      overwritten later by attn_out before gemm_bt reads it)
//   qfB   bf16 [64,4096,64]   @ 43008000   size  33554432
//   kfB   bf16 [64,4096,64]   @ 76562432   size  33554432
//   vfB   bf16 [64,4096,64]   @ 110116864  size  33554432
//   xB    bf16 [16384,1024]   @ 143671296  size  33554432
//   total 177225728 (~169 MiB)
// ---------------------------------------------------------------------------
extern "C" void kernel_launch(void* const* d_in, const int* in_sizes, int n_in,
                              void* d_out, int out_size, void* d_ws, size_t ws_size,
                              hipStream_t stream) {
  if (ws_size < 177225728ULL) return;

  const float* x = (const float*)d_in[0];
  const float* Wqkv = (const float*)d_in[1];
  const float* Wout = (const float*)d_in[2];
  float* out = (float*)d_out;
  char* ws = (char*)d_ws;

  float* kvg = (float*)(ws);
  float* ksumg = (float*)(ws + 1048576);
  bf16* WqkvT = (bf16*)(ws + 1064960);
  bf16* WoutT = (bf16*)(ws + 7356416);
  bf16* attn = (bf16*)(ws + 9453568);
  float2* ctab = (float2*)(ws + 9453568);   // aliases attn head; see layout note
  bf16* qfB = (bf16*)(ws + 43008000);
  bf16* kfB = (bf16*)(ws + 76562432);
  bf16* vfB = (bf16*)(ws + 110116864);
  bf16* xB = (bf16*)(ws + 143671296);

  hipMemsetAsync(ws, 0, 1048576 + 16384, stream);

  rope_tab<<<512, 256, 0, stream>>>(ctab);
  f32_to_bf16<<<16777216 / (256 * 8), 256, 0, stream>>>(x, xB);
  transpose_f32_bf16<<<dim3(3072 / 32, 1024 / 32), 256, 0, stream>>>(Wqkv, WqkvT, 1024, 3072);
  transpose_f32_bf16<<<dim3(1024 / 32, 1024 / 32), 256, 0, stream>>>(Wout, WoutT, 1024, 1024);

  // qkv = x @ W_qkv with fused rope/scale/elu+1 -> head-major qf/kf/vf
  gemm_qkv_fused<<<dim3(3072 / 256, 16384 / 256), 512, 0, stream>>>(xB, WqkvT, ctab, qfB, kfB, vfB);

  // linear attention core
  attn_kv<<<dim3(64, 16), 256, 0, stream>>>(kfB, vfB, kvg, ksumg);
  attn_out<<<dim3(64, 64), 256, 0, stream>>>(qfB, kvg, ksumg, attn);

  // y = attn @ W_out -> fp32 d_out
  gemm_bt_f32<<<dim3(1024 / 256, 16384 / 256), 512, 0, stream>>>(attn, WoutT, out, 1024, 1024);
}